// Round 6
// baseline (228.663 us; speedup 1.0000x reference)
//
#include <hip/hip_runtime.h>
#include <hip/hip_fp16.h>

// VolumeNormalizer: out[b] = v[b] / (sum_t |det(tet)| / 6)^(1/3)
// B=64, N_VERTS=100000 (ROW=300000 floats/row), N_TETS=200000.
//
// R5b: gather-instruction-count attack. R2 vs R4 showed the reduce cost is
// ~52us per 1.8M gather instrs + ~13us per 230MB — instruction-bound.
// Layout xt6[v][b][x,y,z] (fp16, 6B/batch, 384B/vertex): one dwordx3
// per vertex per TET-PAIR (lane = 2 batches, half-wave = tet of pair)
// -> 1.5 gather instr/tet (was 9), same bytes as R4.
// (R5 compile fix: ext_vector elements aren't addressable -> union reinterpret.)

constexpr int NV   = 100000;
constexpr int NT   = 200000;
constexpr int NB   = 64;
constexpr int ROW  = 3 * NV;     // 300000 coords per batch row
constexpr int ROW4 = ROW / 4;    // 75000 float4 per row (exact)

typedef float vfloat4 __attribute__((ext_vector_type(4)));
typedef unsigned int uint3v __attribute__((ext_vector_type(3)));

union gpack { uint3v v; __half h[6]; };

// x (f32, batch-major) -> xt6 (f16): half index = v*192 + b*3 + c.
// Block handles 32 vertices (96 coords) x 64 batches; output region is
// 6144 halves = 12288 B contiguous -> coalesced uint2 stores.
__global__ __launch_bounds__(256) void transpose_kernel(
    const float* __restrict__ x, __half* __restrict__ xt, float* __restrict__ ws)
{
    __shared__ float tile[96][65];               // [coord within block][batch]
    if (blockIdx.x == 0 && threadIdx.x < NB) ws[threadIdx.x] = 0.0f;

    const int v0 = blockIdx.x * 32;
    const int c0 = v0 * 3;                        // 96 coords per block

    // read: 6144 elems, coalesced runs along coords
    #pragma unroll
    for (int k = 0; k < 24; ++k) {
        const int idx = threadIdx.x + k * 256;
        const int b   = idx / 96;
        const int cc  = idx - b * 96;
        tile[cc][b] = x[(size_t)b * ROW + c0 + cc];
    }
    __syncthreads();

    // write: 1536 uint2 (4 halves each), fully coalesced & contiguous
    uint2* outp = (uint2*)(xt + (size_t)v0 * 192);
    #pragma unroll
    for (int k = 0; k < 6; ++k) {
        const int j = threadIdx.x + k * 256;
        union { uint2 u; __half h[4]; } pk;
        #pragma unroll
        for (int i = 0; i < 4; ++i) {
            const int o   = 4 * j + i;            // half offset within block region
            const int dv  = o / 192;              // vertex within block
            const int rem = o - dv * 192;
            const int b   = rem / 3;
            const int c   = rem - b * 3;
            pk.h[i] = __float2half_rn(tile[3 * dv + c][b]);
        }
        outp[j] = pk.u;
    }
}

// lane l: batches 2*(l&31), 2*(l&31)+1 ; half-wave (l>>5): tet 2p / 2p+1.
// Per tet-pair: 1 dwordx3 index load + 3 dwordx3 vertex gathers.
__global__ __launch_bounds__(256) void vol_reduce_kernel(
    const __half* __restrict__ xt,
    const int*    __restrict__ M,
    float*        __restrict__ ws)
{
    const int lane = threadIdx.x & 63;
    const int wib  = threadIdx.x >> 6;
    const int wid  = blockIdx.x * 4 + wib;
    const int nw   = gridDim.x * 4;
    const int NP   = NT / 2;                      // 100000 tet pairs
    const int chunk = (NP + nw - 1) / nw;
    const int p0 = wid * chunk;
    const int p1 = min(NP, p0 + chunk);

    const int hsel = lane >> 5;                   // which tet of the pair
    const int bl   = lane & 31;                   // batch pair id
    const __half* __restrict__ base = xt + bl * 6;

    float accA = 0.0f, accB = 0.0f;
    #pragma unroll 4
    for (int p = p0; p < p1; ++p) {
        const int t = 2 * p + hsel;
        const uint3v mi = *(const uint3v*)(M + 3 * t);     // 12B, aligned

        gpack g0, g1, g2;
        g0.v = *(const uint3v*)(base + (size_t)mi.x * 192);
        g1.v = *(const uint3v*)(base + (size_t)mi.y * 192);
        g2.v = *(const uint3v*)(base + (size_t)mi.z * 192);

        // h = {xA,yA,zA,xB,yB,zB}
        // batch A
        {
            const float a00=__half2float(g0.h[0]), a01=__half2float(g0.h[1]), a02=__half2float(g0.h[2]);
            const float a10=__half2float(g1.h[0]), a11=__half2float(g1.h[1]), a12=__half2float(g1.h[2]);
            const float a20=__half2float(g2.h[0]), a21=__half2float(g2.h[1]), a22=__half2float(g2.h[2]);
            accA += fabsf(a00*(a11*a22 - a12*a21)
                        - a01*(a10*a22 - a12*a20)
                        + a02*(a10*a21 - a11*a20));
        }
        // batch B
        {
            const float a00=__half2float(g0.h[3]), a01=__half2float(g0.h[4]), a02=__half2float(g0.h[5]);
            const float a10=__half2float(g1.h[3]), a11=__half2float(g1.h[4]), a12=__half2float(g1.h[5]);
            const float a20=__half2float(g2.h[3]), a21=__half2float(g2.h[4]), a22=__half2float(g2.h[5]);
            accB += fabsf(a00*(a11*a22 - a12*a21)
                        - a01*(a10*a22 - a12*a20)
                        + a02*(a10*a21 - a11*a20));
        }
    }

    // combine the two half-waves (same batches, different tets)
    accA += __shfl_xor(accA, 32);
    accB += __shfl_xor(accB, 32);

    __shared__ float sacc[4][NB];
    if (lane < 32) {
        sacc[wib][2 * bl]     = accA;
        sacc[wib][2 * bl + 1] = accB;
    }
    __syncthreads();
    if (threadIdx.x < NB)
        atomicAdd(&ws[threadIdx.x],
                  sacc[0][threadIdx.x] + sacc[1][threadIdx.x] +
                  sacc[2][threadIdx.x] + sacc[3][threadIdx.x]);
}

__global__ __launch_bounds__(256) void scale_kernel(
    const vfloat4* __restrict__ x,
    const float*   __restrict__ ws,
    vfloat4*       __restrict__ out)
{
    const int idx = blockIdx.x * 256 + threadIdx.x;
    const int b   = idx / ROW4;
    const float s = cbrtf(6.0f / ws[b]);
    vfloat4 vv = x[idx];
    vv *= s;
    __builtin_nontemporal_store(vv, &out[idx]);
}

extern "C" void kernel_launch(void* const* d_in, const int* in_sizes, int n_in,
                              void* d_out, int out_size, void* d_ws, size_t ws_size,
                              hipStream_t stream)
{
    const float* x   = (const float*)d_in[0];  // (64, 300000) f32
    const int*   M   = (const int*)d_in[1];    // (200000, 3) int32
    float*       out = (float*)d_out;
    float*       ws  = (float*)d_ws;           // ws[0..63] = per-batch sums
    __half*      xt  = (__half*)(ws + 256);    // 38.4 MB fp16, layout v*192+b*3+c

    transpose_kernel<<<NV / 32, 256, 0, stream>>>(x, xt, ws);     // 3125 blocks

    vol_reduce_kernel<<<2048, 256, 0, stream>>>(xt, M, ws);       // 8192 waves

    scale_kernel<<<NB * ROW4 / 256, 256, 0, stream>>>((const vfloat4*)x, ws, (vfloat4*)out);
}

// Round 7
// 218.929 us; speedup vs baseline: 1.0445x; 1.0445x over previous
//
#include <hip/hip_runtime.h>
#include <hip/hip_fp16.h>

// VolumeNormalizer: out[b] = v[b] / (sum_t |det(tet)| / 6)^(1/3)
// B=64, N_VERTS=100000 (ROW=300000 floats/row), N_TETS=200000.
//
// R7: reduce reverted to R4's best-known form (xt[c*64+b] fp16, lane=batch,
// wave-uniform tet loop + readfirstlane so index loads go scalar).
// Transpose rebuilt: 64x64 tile, contiguous 8KB output region per block,
// shift/mask indexing, coalesced uint2 stores. (R6 showed reduce is bound
// by a ~3.5 TB/s line-fill ceiling, insensitive to instr count; the real
// slack was the ~155us of transpose+scale.)

constexpr int NV   = 100000;
constexpr int NT   = 200000;
constexpr int NB   = 64;
constexpr int ROW  = 3 * NV;     // 300000 coords per batch row
constexpr int ROW4 = ROW / 4;    // 75000 float4 per row (exact)

typedef float vfloat4 __attribute__((ext_vector_type(4)));

// x (f32, batch-major) -> xt (f16, coord-major: xt[c*64 + b]); zeroes ws.
// Block: 64 coords x 64 batches. Output = 8192B contiguous region.
__global__ __launch_bounds__(256) void transpose_kernel(
    const float* __restrict__ x, __half* __restrict__ xt, float* __restrict__ ws)
{
    __shared__ float tile[64][65];                 // [coord][batch], +1 pad
    if (blockIdx.x == 0 && threadIdx.x < NB) ws[threadIdx.x] = 0.0f;

    const int c0 = blockIdx.x * 64;
    const int c  = threadIdx.x & 63;               // lane = coord
    const int b0 = threadIdx.x >> 6;               // wave = batch quarter

    if (c0 + c < ROW) {
        #pragma unroll
        for (int k = 0; k < 16; ++k) {
            const int b = b0 + 4 * k;              // wave reads 256B runs
            tile[c][b] = x[(size_t)b * ROW + c0 + c];
        }
    }
    __syncthreads();

    // write 1024 uint2 (4 halves each): halves [4j..4j+4) of the block region
    uint2* outp = (uint2*)(xt + (size_t)c0 * NB);
    #pragma unroll
    for (int k = 0; k < 4; ++k) {
        const int j  = threadIdx.x + k * 256;
        const int cc = j >> 4;                     // coord within block
        const int bb = (j & 15) * 4;               // batch
        if (c0 + cc < ROW) {
            union { uint2 u; __half2 h[2]; } pk;
            pk.h[0] = __floats2half2_rn(tile[cc][bb],     tile[cc][bb + 1]);
            pk.h[1] = __floats2half2_rn(tile[cc][bb + 2], tile[cc][bb + 3]);
            outp[j] = pk.u;                        // 512B/wave contiguous
        }
    }
}

// lane = batch; per tet: 3 wave-uniform (scalar) index loads + 9 coalesced
// 128B fp16 gathers. fp32 math.
__global__ __launch_bounds__(256, 8) void vol_reduce_kernel(
    const __half* __restrict__ xt,
    const int*    __restrict__ M,
    float*        __restrict__ ws)
{
    const int lane = threadIdx.x & 63;
    const int wib  = threadIdx.x >> 6;
    // wave-uniform: lets the compiler prove index loads scalar (s_load)
    const int wid  = __builtin_amdgcn_readfirstlane(blockIdx.x * 4 + wib);
    const int nw   = gridDim.x * 4;
    const int chunk = (NT + nw - 1) / nw;
    const int t0 = wid * chunk;
    const int t1 = min(NT, t0 + chunk);

    const __half* __restrict__ base = xt + lane;
    float acc = 0.0f;
    #pragma unroll 4
    for (int t = t0; t < t1; ++t) {
        const int i0 = M[3 * t + 0];
        const int i1 = M[3 * t + 1];
        const int i2 = M[3 * t + 2];
        const __half* p0 = base + (size_t)i0 * 192;   // (3*i)*64 halves
        const __half* p1 = base + (size_t)i1 * 192;
        const __half* p2 = base + (size_t)i2 * 192;
        const float a00 = __half2float(p0[0]);
        const float a01 = __half2float(p0[64]);
        const float a02 = __half2float(p0[128]);
        const float a10 = __half2float(p1[0]);
        const float a11 = __half2float(p1[64]);
        const float a12 = __half2float(p1[128]);
        const float a20 = __half2float(p2[0]);
        const float a21 = __half2float(p2[64]);
        const float a22 = __half2float(p2[128]);
        const float det = a00 * (a11 * a22 - a12 * a21)
                        - a01 * (a10 * a22 - a12 * a20)
                        + a02 * (a10 * a21 - a11 * a20);
        acc += fabsf(det);
    }

    __shared__ float sacc[4][NB];
    sacc[wib][lane] = acc;
    __syncthreads();
    if (threadIdx.x < NB)
        atomicAdd(&ws[threadIdx.x],
                  sacc[0][threadIdx.x] + sacc[1][threadIdx.x] +
                  sacc[2][threadIdx.x] + sacc[3][threadIdx.x]);
}

__global__ __launch_bounds__(256) void scale_kernel(
    const vfloat4* __restrict__ x,
    const float*   __restrict__ ws,
    vfloat4*       __restrict__ out)
{
    const int idx = blockIdx.x * 256 + threadIdx.x;
    const int b   = idx / ROW4;
    const float s = cbrtf(6.0f / ws[b]);
    vfloat4 vv = x[idx];
    vv *= s;
    __builtin_nontemporal_store(vv, &out[idx]);
}

extern "C" void kernel_launch(void* const* d_in, const int* in_sizes, int n_in,
                              void* d_out, int out_size, void* d_ws, size_t ws_size,
                              hipStream_t stream)
{
    const float* x   = (const float*)d_in[0];  // (64, 300000) f32
    const int*   M   = (const int*)d_in[1];    // (200000, 3) int32
    float*       out = (float*)d_out;
    float*       ws  = (float*)d_ws;           // ws[0..63] = per-batch sums
    __half*      xt  = (__half*)(ws + 256);    // 38.4 MB fp16, layout c*64+b

    transpose_kernel<<<(ROW + 63) / 64, 256, 0, stream>>>(x, xt, ws);  // 4688 blocks

    vol_reduce_kernel<<<2048, 256, 0, stream>>>(xt, M, ws);            // 8192 waves

    scale_kernel<<<NB * ROW4 / 256, 256, 0, stream>>>((const vfloat4*)x, ws, (vfloat4*)out);
}